// Round 8
// baseline (956.478 us; speedup 1.0000x reference)
//
#include <hip/hip_runtime.h>
#include <math.h>

#define N_NODES 50000
#define F_IN 256
#define HID 128
#define NH 8
#define HD 16
#define NCLS 64
#define NEDGE 1250000
#define NB 44
#define RATIO 0.15075567228888181f
#define EPS_F 1e-4f
#define NCHUNK 196   // ceil(N_NODES/256)
#define NROW (NCHUNK * 4)  // partial rows per head = 784

typedef short short8 __attribute__((ext_vector_type(8)));
typedef float f32x4 __attribute__((ext_vector_type(4)));
typedef unsigned short u16;

// ---------- helpers ----------
__device__ inline unsigned fkey(float f) {
    unsigned u = __float_as_uint(f);
    return (u & 0x80000000u) ? ~u : (u | 0x80000000u);
}
__device__ inline float funkey(unsigned k) {
    unsigned u = (k & 0x80000000u) ? (k ^ 0x80000000u) : ~k;
    return __uint_as_float(u);
}
__device__ inline float elu_f(float v) { return v > 0.f ? v : expm1f(v); }
__device__ inline u16 f2bf(float f) {
    unsigned u = __float_as_uint(f);
    unsigned r = (u + 0x7fffu + ((u >> 16) & 1u)) >> 16;  // RNE
    return (u16)r;
}

// ---------- convert data fp32 -> bf16 ----------
__global__ __launch_bounds__(256) void cvt_data_kernel(
    const float* __restrict__ d, u16* __restrict__ o)
{
    int idx = blockIdx.x * 256 + threadIdx.x;   // one per 8 floats
    if (idx >= N_NODES * 256 / 8) return;
    const float4* p = (const float4*)(d + (size_t)idx * 8);
    float4 v0 = p[0], v1 = p[1];
    u16 t[8];
    t[0] = f2bf(v0.x); t[1] = f2bf(v0.y); t[2] = f2bf(v0.z); t[3] = f2bf(v0.w);
    t[4] = f2bf(v1.x); t[5] = f2bf(v1.y); t[6] = f2bf(v1.z); t[7] = f2bf(v1.w);
    *(short8*)(o + (size_t)idx * 8) = *(short8*)t;
}

// ---------- pack W (transposed, bf16) + bias for fused QKV+lin1 GEMM ----------
__global__ __launch_bounds__(256) void pack_wt_kernel(
    const float* __restrict__ qw, const float* __restrict__ kw,
    const float* __restrict__ vw, const float* __restrict__ lw,
    const float* __restrict__ qb, const float* __restrict__ kb,
    const float* __restrict__ vb, const float* __restrict__ lb,
    u16* __restrict__ Wt, float* __restrict__ bcat)
{
    int idx = blockIdx.x * 256 + threadIdx.x;
    if (idx < 512 * 256) {
        int n = idx >> 8, k = idx & 255;
        int sel = n >> 7, jj = n & 127;
        const float* w = sel == 0 ? qw : sel == 1 ? kw : sel == 2 ? vw : lw;
        Wt[idx] = f2bf(w[k * 128 + jj]);
    }
    if (idx < 512) {
        int sel = idx >> 7, jj = idx & 127;
        const float* b = sel == 0 ? qb : sel == 1 ? kb : sel == 2 ? vb : lb;
        bcat[idx] = b[jj];
    }
}

// ---------- pack lin2_w transposed bf16 ----------
__global__ __launch_bounds__(256) void pack_wt2_kernel(
    const float* __restrict__ w2, const float* __restrict__ b2in,
    u16* __restrict__ Wt2, float* __restrict__ b2)
{
    int idx = blockIdx.x * 256 + threadIdx.x;
    if (idx < 64 * 256) {
        int n = idx >> 8, k = idx & 255;
        Wt2[idx] = f2bf(w2[k * 64 + n]);
    }
    if (idx < 64) b2[idx] = b2in[idx];
}

// ---------- bf16 MFMA GEMM1: sections 0=Q,1=K (fp32->B1qk), 2=V (bf16), 3=lin1 (elu bf16->hbuf) ----------
#define LDA 40
__global__ __launch_bounds__(256) void gemm1_mfma(
    const u16* __restrict__ A, const u16* __restrict__ Wt,
    const float* __restrict__ bias, float* __restrict__ B1qk,
    u16* __restrict__ Vbf, u16* __restrict__ hbuf, int M)
{
    __shared__ u16 As[128 * LDA];
    __shared__ u16 Bs[128 * LDA];
    int tid = threadIdx.x;
    int wave = tid >> 6, lane = tid & 63;
    int quad = lane >> 4, lrow = lane & 15;
    int m0 = blockIdx.x * 128;
    int sec = blockIdx.y;
    int n0 = sec * 128;
    int wm = (wave & 1) * 64, wn = (wave >> 1) * 64;

    f32x4 acc[4][4];
#pragma unroll
    for (int i = 0; i < 4; i++)
#pragma unroll
        for (int j = 0; j < 4; j++) acc[i][j] = (f32x4){0.f, 0.f, 0.f, 0.f};

    int r = tid >> 1;
    int cc = (tid & 1) * 16;

    for (int k0 = 0; k0 < 256; k0 += 32) {
        short8 x0 = (short8)0, x1 = (short8)0;
        int row = m0 + r;
        if (row < M) {
            const short8* p = (const short8*)(A + (size_t)row * 256 + k0 + cc);
            x0 = p[0]; x1 = p[1];
        }
        *(short8*)&As[r * LDA + cc] = x0;
        *(short8*)&As[r * LDA + cc + 8] = x1;
        const short8* q = (const short8*)(Wt + (size_t)(n0 + r) * 256 + k0 + cc);
        *(short8*)&Bs[r * LDA + cc] = q[0];
        *(short8*)&Bs[r * LDA + cc + 8] = q[1];
        __syncthreads();

        short8 af[4], bfr[4];
#pragma unroll
        for (int i = 0; i < 4; i++)
            af[i] = *(const short8*)&As[(wm + i * 16 + lrow) * LDA + quad * 8];
#pragma unroll
        for (int j = 0; j < 4; j++)
            bfr[j] = *(const short8*)&Bs[(wn + j * 16 + lrow) * LDA + quad * 8];
#pragma unroll
        for (int i = 0; i < 4; i++)
#pragma unroll
            for (int j = 0; j < 4; j++)
                acc[i][j] = __builtin_amdgcn_mfma_f32_16x16x32_bf16(af[i], bfr[j], acc[i][j], 0, 0, 0);
        __syncthreads();
    }

#pragma unroll
    for (int j = 0; j < 4; j++) {
        int col = wn + j * 16 + lrow;          // 0..127 within section
        float bj = bias[n0 + col];
#pragma unroll
        for (int i = 0; i < 4; i++) {
#pragma unroll
            for (int reg = 0; reg < 4; reg++) {
                int row = m0 + wm + i * 16 + quad * 4 + reg;
                if (row >= M) continue;
                float v = acc[i][j][reg] + bj;
                if (sec <= 1)      B1qk[(size_t)row * 256 + sec * 128 + col] = v;
                else if (sec == 2) Vbf[(size_t)row * 128 + col] = f2bf(v);
                else               hbuf[(size_t)row * 256 + col] = f2bf(elu_f(v));
            }
        }
    }
}

// ---------- bf16 MFMA GEMM2 (lin2): [N,256]@[256,64] + bias, elu -> xbuf fp32 + bf16 ----------
__global__ __launch_bounds__(256) void gemm2_mfma(
    const u16* __restrict__ A, const u16* __restrict__ Wt2,
    const float* __restrict__ b2, float* __restrict__ xbuf,
    u16* __restrict__ xbf, int M)
{
    __shared__ u16 As[128 * LDA];
    __shared__ u16 Bs[64 * LDA];
    int tid = threadIdx.x;
    int wave = tid >> 6, lane = tid & 63;
    int quad = lane >> 4, lrow = lane & 15;
    int m0 = blockIdx.x * 128;
    int wm = (wave & 1) * 64, wn = (wave >> 1) * 32;

    f32x4 acc[4][2];
#pragma unroll
    for (int i = 0; i < 4; i++)
#pragma unroll
        for (int j = 0; j < 2; j++) acc[i][j] = (f32x4){0.f, 0.f, 0.f, 0.f};

    int r = tid >> 1;
    int cc = (tid & 1) * 16;

    for (int k0 = 0; k0 < 256; k0 += 32) {
        short8 x0 = (short8)0, x1 = (short8)0;
        int row = m0 + r;
        if (row < M) {
            const short8* p = (const short8*)(A + (size_t)row * 256 + k0 + cc);
            x0 = p[0]; x1 = p[1];
        }
        *(short8*)&As[r * LDA + cc] = x0;
        *(short8*)&As[r * LDA + cc + 8] = x1;
        if (tid < 128) {
            const short8* q = (const short8*)(Wt2 + (size_t)r * 256 + k0 + cc);
            *(short8*)&Bs[r * LDA + cc] = q[0];
            *(short8*)&Bs[r * LDA + cc + 8] = q[1];
        }
        __syncthreads();

        short8 af[4], bfr[2];
#pragma unroll
        for (int i = 0; i < 4; i++)
            af[i] = *(const short8*)&As[(wm + i * 16 + lrow) * LDA + quad * 8];
#pragma unroll
        for (int j = 0; j < 2; j++)
            bfr[j] = *(const short8*)&Bs[(wn + j * 16 + lrow) * LDA + quad * 8];
#pragma unroll
        for (int i = 0; i < 4; i++)
#pragma unroll
            for (int j = 0; j < 2; j++)
                acc[i][j] = __builtin_amdgcn_mfma_f32_16x16x32_bf16(af[i], bfr[j], acc[i][j], 0, 0, 0);
        __syncthreads();
    }

#pragma unroll
    for (int j = 0; j < 2; j++) {
        int col = wn + j * 16 + lrow;   // 0..63
        float bj = b2[col];
#pragma unroll
        for (int i = 0; i < 4; i++) {
#pragma unroll
            for (int reg = 0; reg < 4; reg++) {
                int row = m0 + wm + i * 16 + quad * 4 + reg;
                if (row >= M) continue;
                float v = elu_f(acc[i][j][reg] + bj);
                xbuf[(size_t)row * 64 + col] = v;
                xbf[(size_t)row * 64 + col] = f2bf(v);
            }
        }
    }
}

// ---------- K-side global max of dash per head (proj via scalar loads) ----------
__global__ __launch_bounds__(256) void kmax_kernel(
    const float* __restrict__ B1qk, const float* __restrict__ proj,
    unsigned* __restrict__ kmax)
{
    __shared__ unsigned smax[NH];
    int tid = threadIdx.x;
    if (tid < NH) smax[tid] = 0u;
    __syncthreads();
    int g = blockIdx.x * 256 + tid;
    if (g < N_NODES * NH) {
        int n = g >> 3, h = g & 7;
        const float* kp = B1qk + (size_t)n * 256 + 128 + h * 16;
        float x[16];
#pragma unroll
        for (int i = 0; i < 16; i += 4) *(float4*)&x[i] = *(const float4*)(kp + i);
        float mx = -1e30f;
        for (int m = 0; m < NB; m++) {
            float d = 0.f;
#pragma unroll
            for (int i = 0; i < 16; i++) d += x[i] * proj[m * 16 + i];
            mx = fmaxf(mx, d);
        }
        atomicMax(&smax[h], fkey(mx * 0.5f));
    }
    __syncthreads();
    if (tid < NH) atomicMax(&kmax[tid], smax[tid]);
}

// ---------- K-side stage A: kp -> bf16 LDS -> MFMA -> per-wave partials (NO atomics) ----------
#define KLD 264   // LDS row stride (bf16 elems): 528B -> 4-bank shift/row, conflict-free b128
__global__ __launch_bounds__(256) void kstats_kernel(
    const float* __restrict__ B1qk, const u16* __restrict__ Vbf,
    const float* __restrict__ proj, const unsigned* __restrict__ kmax,
    float* __restrict__ partC, float* __restrict__ partK)
{
    __shared__ u16 kpT[48 * KLD];
    __shared__ u16 vT[16 * KLD];
    int h = blockIdx.y;
    int tid = threadIdx.x;
    int wave = tid >> 6, lane = tid & 63;
    int quad = lane >> 4, lrow = lane & 15;

    // zero the pad rows 44..47 of kpT (never written below)
    for (int i = tid; i < 4 * KLD / 2; i += 256) ((unsigned*)&kpT[44 * KLD])[i] = 0u;

    float M = funkey(kmax[h]);
    int n = blockIdx.x * 256 + tid;
    bool valid = n < N_NODES;
    float x[16];
    float diag = 0.f;
    if (valid) {
#pragma unroll
        for (int i = 0; i < 16; i += 4)
            *(float4*)&x[i] = *(const float4*)(B1qk + (size_t)n * 256 + 128 + h * 16 + i);
#pragma unroll
        for (int i = 0; i < 16; i++) diag += x[i] * x[i];
        diag *= 0.125f;
    }
#pragma unroll 4
    for (int m = 0; m < NB; m++) {
        float kp = 0.f;
        if (valid) {
            float d = 0.f;
#pragma unroll
            for (int i = 0; i < 16; i++) d += x[i] * proj[m * 16 + i];
            kp = RATIO * (expf(0.5f * d - diag - M) + EPS_F);
        }
        kpT[m * KLD + tid] = f2bf(kp);
    }
    // V row (already bf16)
    u16 vv[16];
    if (valid) {
        const short8* pv = (const short8*)(Vbf + (size_t)n * 128 + h * 16);
        *(short8*)&vv[0] = pv[0];
        *(short8*)&vv[8] = pv[1];
    } else {
#pragma unroll
        for (int i = 0; i < 16; i++) vv[i] = 0;
    }
#pragma unroll
    for (int d = 0; d < 16; d++) vT[d * KLD + tid] = vv[d];
    __syncthreads();

    f32x4 accC[3], accK[3];
#pragma unroll
    for (int t = 0; t < 3; t++) { accC[t] = (f32x4){0,0,0,0}; accK[t] = (f32x4){0,0,0,0}; }

    short8 ones = (short8)0;
    if (lrow == 0) {
#pragma unroll
        for (int i = 0; i < 8; i++) ones[i] = (short)0x3F80;  // bf16 1.0
    }

    // MFMA: this wave handles node-subchunks 2*wave, 2*wave+1 (K dim = nodes)
#pragma unroll
    for (int c2 = 0; c2 < 2; c2++) {
        int c = wave * 2 + c2;
        short8 bfr = *(const short8*)&vT[lrow * KLD + c * 32 + quad * 8];
#pragma unroll
        for (int t = 0; t < 3; t++) {
            short8 af = *(const short8*)&kpT[(t * 16 + lrow) * KLD + c * 32 + quad * 8];
            accC[t] = __builtin_amdgcn_mfma_f32_16x16x32_bf16(af, bfr, accC[t], 0, 0, 0);
            accK[t] = __builtin_amdgcn_mfma_f32_16x16x32_bf16(af, ones, accK[t], 0, 0, 0);
        }
    }

    // stream per-wave partials; entry e = m*16+col, row = h*784 + blockIdx.x*4 + wave
    int prow = (h * NCHUNK + blockIdx.x) * 4 + wave;
    float* P = partC + (size_t)prow * 768;
#pragma unroll
    for (int t = 0; t < 3; t++)
#pragma unroll
        for (int reg = 0; reg < 4; reg++)
            P[t * 256 + quad * 64 + reg * 16 + lrow] = accC[t][reg];
    if (lrow == 0) {
        float* P2 = partK + (size_t)prow * 48;
#pragma unroll
        for (int t = 0; t < 3; t++)
#pragma unroll
            for (int reg = 0; reg < 4; reg++)
                P2[t * 16 + quad * 4 + reg] = accK[t][reg];
    }
}

// ---------- K-side stage B: reduce partials -> ctx, kcum ----------
__global__ __launch_bounds__(256) void kreduce_kernel(
    const float* __restrict__ partC, const float* __restrict__ partK,
    float* __restrict__ kcum, float* __restrict__ ctx)
{
    int b = blockIdx.x;
    int tid = threadIdx.x;
    if (b < 24) {
        int g = b * 256 + tid;            // [0, 8*768)
        int h = g / 768, e = g % 768;
        int m = e >> 4, col = e & 15;
        const float* p = partC + (size_t)h * NROW * 768 + e;
        float s0 = 0.f, s1 = 0.f, s2 = 0.f, s3 = 0.f;
        for (int i = 0; i < NROW; i += 4) {
            s0 += p[(size_t)(i + 0) * 768];
            s1 += p[(size_t)(i + 1) * 768];
            s2 += p[(size_t)(i + 2) * 768];
            s3 += p[(size_t)(i + 3) * 768];
        }
        if (m < NB) ctx[h * NB * HD + m * 16 + col] = (s0 + s1) + (s2 + s3);
    } else {
        int g = (b - 24) * 256 + tid;     // need 8*48 = 384
        if (g < NH * 48) {
            int h = g / 48, m = g % 48;
            const float* p = partK + (size_t)h * NROW * 48 + m;
            float s0 = 0.f, s1 = 0.f, s2 = 0.f, s3 = 0.f;
            for (int i = 0; i < NROW; i += 4) {
                s0 += p[(size_t)(i + 0) * 48];
                s1 += p[(size_t)(i + 1) * 48];
                s2 += p[(size_t)(i + 2) * 48];
                s3 += p[(size_t)(i + 3) * 48];
            }
            if (m < NB) kcum[h * NB + m] = (s0 + s1) + (s2 + s3);
        }
    }
}

// ---------- Q-side + attention output (scalar proj/ctx/kcum, bf16 out to hbuf) ----------
__global__ __launch_bounds__(256) void attn_out_kernel(
    const float* __restrict__ B1qk, const float* __restrict__ proj,
    const float* __restrict__ kcum, const float* __restrict__ ctx,
    u16* __restrict__ hbuf)
{
    int h = blockIdx.y;
    int tid = threadIdx.x;
    int n = blockIdx.x * 256 + tid;
    if (n >= N_NODES) return;
    float x[16];
#pragma unroll
    for (int i = 0; i < 16; i += 4)
        *(float4*)&x[i] = *(const float4*)(B1qk + (size_t)n * 256 + h * 16 + i);
    float diag = 0.f;
#pragma unroll
    for (int i = 0; i < 16; i++) diag += x[i] * x[i];
    diag *= 0.125f;
    float dash[NB];
    float mx = -1e30f;
#pragma unroll 4
    for (int m = 0; m < NB; m++) {
        float d = 0.f;
#pragma unroll
        for (int i = 0; i < 16; i++) d += x[i] * proj[m * 16 + i];
        d *= 0.5f;
        dash[m] = d;
        mx = fmaxf(mx, d);
    }
    float den = 0.f;
    float outv[16];
#pragma unroll
    for (int d = 0; d < 16; d++) outv[d] = 0.f;
#pragma unroll 4
    for (int m = 0; m < NB; m++) {
        float q = RATIO * (expf(dash[m] - diag - mx) + EPS_F);
        den += q * kcum[h * NB + m];
#pragma unroll
        for (int d = 0; d < 16; d++) outv[d] += q * ctx[h * NB * HD + m * 16 + d];
    }
    float dinv = 1.f / den;
    u16 ob[16];
#pragma unroll
    for (int d = 0; d < 16; d++) ob[d] = f2bf(elu_f(outv[d] * dinv));
    u16* dst = hbuf + (size_t)n * 256 + 128 + h * 16;
    *(short8*)dst = *(short8*)&ob[0];
    *(short8*)(dst + 8) = *(short8*)&ob[8];
}

// ---------- APPNP: degree / dis / scan / CSR fill / hop ----------
__global__ __launch_bounds__(256) void deg_kernel(const int* __restrict__ ei, unsigned* __restrict__ deg)
{
    int e = blockIdx.x * 256 + threadIdx.x;
    if (e < NEDGE) atomicAdd(&deg[ei[NEDGE + e]], 1u);
}
__global__ __launch_bounds__(256) void dis_kernel(const unsigned* __restrict__ deg, float* __restrict__ dis)
{
    int i = blockIdx.x * 256 + threadIdx.x;
    if (i < N_NODES) dis[i] = rsqrtf((float)(deg[i] + 1u));
}
__global__ __launch_bounds__(256) void scan1_kernel(const unsigned* __restrict__ deg, unsigned* __restrict__ bsum)
{
    __shared__ unsigned s[256];
    int i = blockIdx.x * 256 + threadIdx.x;
    unsigned v = (i < N_NODES) ? deg[i] : 0u;
    s[threadIdx.x] = v;
    __syncthreads();
    for (int d = 128; d > 0; d >>= 1) {
        if (threadIdx.x < d) s[threadIdx.x] += s[threadIdx.x + d];
        __syncthreads();
    }
    if (threadIdx.x == 0) bsum[blockIdx.x] = s[0];
}
__global__ __launch_bounds__(256) void scan2_kernel(const unsigned* __restrict__ bsum, unsigned* __restrict__ boff, int nb)
{
    __shared__ unsigned s[256];
    int t = threadIdx.x;
    unsigned v = (t < nb) ? bsum[t] : 0u;
    s[t] = v;
    __syncthreads();
    for (int d = 1; d < 256; d <<= 1) {
        unsigned x = (t >= d) ? s[t - d] : 0u;
        __syncthreads();
        s[t] += x;
        __syncthreads();
    }
    boff[t] = s[t] - v;
}
__global__ __launch_bounds__(256) void scan3_kernel(
    const unsigned* __restrict__ deg, const unsigned* __restrict__ boff,
    unsigned* __restrict__ offsets)
{
    __shared__ unsigned s[256];
    int t = threadIdx.x;
    int i = blockIdx.x * 256 + t;
    unsigned v = (i < N_NODES) ? deg[i] : 0u;
    s[t] = v;
    __syncthreads();
    for (int d = 1; d < 256; d <<= 1) {
        unsigned x = (t >= d) ? s[t - d] : 0u;
        __syncthreads();
        s[t] += x;
        __syncthreads();
    }
    unsigned excl = s[t] - v + boff[blockIdx.x];
    if (i < N_NODES) offsets[i] = excl;
    if (i == N_NODES - 1) offsets[N_NODES] = excl + v;
}
__global__ __launch_bounds__(256) void fill_csr_kernel(
    const int* __restrict__ ei, const unsigned* __restrict__ offsets,
    unsigned* __restrict__ cursor, const float* __restrict__ dis,
    int2* __restrict__ csr_ed)
{
    int e = blockIdx.x * 256 + threadIdx.x;
    if (e >= NEDGE) return;
    int r = ei[e], c = ei[NEDGE + e];
    unsigned pos = offsets[c] + atomicAdd(&cursor[c], 1u);
    csr_ed[pos] = make_int2(r, __float_as_int(dis[r] * dis[c]));
}
// one wave per node; gathers read bf16 h (2 edges per gather instruction);
// self + x0 + outputs in fp32; bf16 copy written for next hop's gathers
__global__ __launch_bounds__(256) void hop_kernel(
    const u16* __restrict__ hbf, const float* __restrict__ hf,
    const float* __restrict__ x0,
    const unsigned* __restrict__ offsets, const int2* __restrict__ edges,
    const float* __restrict__ dis,
    float* __restrict__ hf_out, u16* __restrict__ hbf_out)
{
    int wave = threadIdx.x >> 6, lane = threadIdx.x & 63;
    int n = blockIdx.x * 4 + wave;
    if (n >= N_NODES) return;
    int half = lane >> 5, fl = lane & 31;   // half: even/odd edges; fl: feature pair
    unsigned e0 = offsets[n], e1 = offsets[n + 1];
    float ax = 0.f, ay = 0.f;
    unsigned e = e0;
    while (e < e1) {
        unsigned cnt = min(64u, e1 - e);
        int2 ev = ((unsigned)lane < cnt) ? edges[e + lane] : make_int2(0, 0);
#pragma unroll 8
        for (unsigned j = 0; j < cnt; j += 2) {
            int jj = (int)j + half;          // pad lanes give w=0, s=0 -> no-op
            int s = __shfl(ev.x, jj);
            float wv = __int_as_float(__shfl(ev.y, jj));
            unsigned u = *(const unsigned*)(hbf + (size_t)s * 64 + fl * 2);
            float lo = __uint_as_float(u << 16);
            float hi = __uint_as_float(u & 0xffff0000u);
            ax += wv * lo;
            ay += wv * hi;
        }
        e += cnt;
    }
    // combine even/odd halves
    ax += __shfl_xor(ax, 32);
    ay += __shfl_xor(ay, 32);
    if (half == 0) {
        float dn = dis[n];
        float2 hs = *(const float2*)(hf + (size_t)n * 64 + fl * 2);
        float2 xs = *(const float2*)(x0 + (size_t)n * 64 + fl * 2);
        float rx = 0.9f * (ax + dn * dn * hs.x) + 0.1f * xs.x;
        float ry = 0.9f * (ay + dn * dn * hs.y) + 0.1f * xs.y;
        *(float2*)(hf_out + (size_t)n * 64 + fl * 2) = make_float2(rx, ry);
        unsigned pu = (unsigned)f2bf(rx) | ((unsigned)f2bf(ry) << 16);
        *(unsigned*)(hbf_out + (size_t)n * 64 + fl * 2) = pu;
    }
}

// ---------- log_softmax + raw copy ----------
__global__ __launch_bounds__(256) void logsoftmax_kernel(
    const float* __restrict__ hf, float* __restrict__ out)
{
    int wave = threadIdx.x >> 6, lane = threadIdx.x & 63;
    int n = blockIdx.x * 4 + wave;
    if (n >= N_NODES) return;
    float v = hf[(size_t)n * 64 + lane];
    float m = v;
    for (int d = 32; d > 0; d >>= 1) m = fmaxf(m, __shfl_xor(m, d));
    float ex = expf(v - m);
    float ssum = ex;
    for (int d = 32; d > 0; d >>= 1) ssum += __shfl_xor(ssum, d);
    out[(size_t)n * 64 + lane] = v - m - logf(ssum);
    out[(size_t)N_NODES * 64 + (size_t)n * 64 + lane] = v;
}

// ---------- launcher ----------
static inline size_t align256(size_t x) { return (x + 255) & ~(size_t)255; }

extern "C" void kernel_launch(void* const* d_in, const int* in_sizes, int n_in,
                              void* d_out, int out_size, void* d_ws, size_t ws_size,
                              hipStream_t stream)
{
    const float* data   = (const float*)d_in[0];
    const int*   ei     = (const int*)d_in[1];
    const float* lin1_w = (const float*)d_in[2];
    const float* lin1_b = (const float*)d_in[3];
    const float* lin2_w = (const float*)d_in[4];
    const float* lin2_b = (const float*)d_in[5];
    const float* q_w = (const float*)d_in[6];
    const float* q_b = (const float*)d_in[7];
    const float* k_w = (const float*)d_in[8];
    const float* k_b = (const float*)d_in[9];
    const float* v_w = (const float*)d_in[10];
    const float* v_b = (const float*)d_in[11];
    const float* proj = (const float*)d_in[12];
    float* out = (float*)d_out;

    char* w = (char*)d_ws;
    auto alloc = [&](size_t bytes) { char* p = w; w += align256(bytes); return p; };
    float*    B1qk    = (float*)alloc((size_t)N_NODES * 256 * 4);
    u16*      Abf     = (u16*)alloc((size_t)N_NODES * 256 * 2);
    u16*      Wt      = (u16*)alloc(512 * 256 * 2);
    float*    bcat    = (float*)alloc(512 * 4);
    u16*      Wt2     = (u16*)alloc(64 * 256 * 2);
    float*    b2      = (float*)alloc(64 * 4);
    u16*      Vbf     = (u16*)alloc((size_t)N_NODES * 128 * 2);
    u16*      hbuf    = (u16*)alloc((size_t)N_NODES * 256 * 2);
    unsigned* kmax    = (unsigned*)alloc(NH * 4);
    float*    kcum    = (float*)alloc((NH * NB + NH * NB * HD) * 4);
    float*    ctx     = kcum + NH * NB;
    float*    partC   = (float*)alloc((size_t)NH * NROW * 768 * 4);
    float*    partK   = (float*)alloc((size_t)NH * NROW * 48 * 4);
    float*    xbuf    = (float*)alloc((size_t)N_NODES * 64 * 4);
    u16*      xbf     = (u16*)alloc((size_t)N_NODES * 64 * 2);
    float*    hA      = (float*)alloc((size_t)N_NODES * 64 * 4);
    float*    hB      = (float*)alloc((size_t)N_NODES * 64 * 4);
    u16*      hbfA    = (u16*)alloc((size_t)N_NODES * 64 * 2);
    u16*      hbfB    = (u16*)alloc((size_t)N_NODES * 64 * 2);
    unsigned* deg     = (unsigned*)alloc((size_t)N_NODES * 4);
    float*    dis     = (float*)alloc((size_t)N_NODES * 4);
    unsigned* offsets = (unsigned*)alloc((size_t)(N_NODES + 1) * 4);
    unsigned* cursor  = (unsigned*)alloc((size_t)N_NODES * 4);
    unsigned* bsum    = (unsigned*)alloc(256 * 4);
    unsigned* boff    = (unsigned*)alloc(256 * 4);
    int2*     csr_ed  = (int2*)alloc((size_t)NEDGE * 8);

    hipMemsetAsync(kmax, 0, NH * 4, stream);
    hipMemsetAsync(deg, 0, (size_t)N_NODES * 4, stream);
    hipMemsetAsync(cursor, 0, (size_t)N_NODES * 4, stream);

    cvt_data_kernel<<<(N_NODES * 256 / 8 + 255) / 256, 256, 0, stream>>>(data, Abf);
    pack_wt_kernel<<<512, 256, 0, stream>>>(q_w, k_w, v_w, lin1_w, q_b, k_b, v_b, lin1_b, Wt, bcat);
    pack_wt2_kernel<<<64, 256, 0, stream>>>(lin2_w, lin2_b, Wt2, b2);

    gemm1_mfma<<<dim3((N_NODES + 127) / 128, 4), 256, 0, stream>>>(
        Abf, Wt, bcat, B1qk, Vbf, hbuf, N_NODES);

    kmax_kernel<<<(N_NODES * NH + 255) / 256, 256, 0, stream>>>(B1qk, proj, kmax);
    kstats_kernel<<<dim3(NCHUNK, NH), 256, 0, stream>>>(
        B1qk, Vbf, proj, kmax, partC, partK);
    kreduce_kernel<<<26, 256, 0, stream>>>(partC, partK, kcum, ctx);
    attn_out_kernel<<<dim3((N_NODES + 255) / 256, NH), 256, 0, stream>>>(
        B1qk, proj, kcum, ctx, hbuf);

    gemm2_mfma<<<dim3((N_NODES + 127) / 128, 1), 256, 0, stream>>>(
        hbuf, Wt2, b2, xbuf, xbf, N_NODES);

    // APPNP prep
    deg_kernel<<<(NEDGE + 255) / 256, 256, 0, stream>>>(ei, deg);
    dis_kernel<<<(N_NODES + 255) / 256, 256, 0, stream>>>(deg, dis);
    int nscan = (N_NODES + 255) / 256;
    scan1_kernel<<<nscan, 256, 0, stream>>>(deg, bsum);
    scan2_kernel<<<1, 256, 0, stream>>>(bsum, boff, nscan);
    scan3_kernel<<<nscan, 256, 0, stream>>>(deg, boff, offsets);
    fill_csr_kernel<<<(NEDGE + 255) / 256, 256, 0, stream>>>(ei, offsets, cursor, dis, csr_ed);

    // 10 hops, ping-pong (bf16 gather table + fp32 carry)
    const float* hf_in = xbuf;
    const u16*   hb_in = xbf;
    float* f_out = hA;
    u16*   b_out = hbfA;
    for (int hop = 0; hop < 10; hop++) {
        hop_kernel<<<N_NODES / 4, 256, 0, stream>>>(
            hb_in, hf_in, xbuf, offsets, csr_ed, dis, f_out, b_out);
        hf_in = f_out;
        hb_in = b_out;
        f_out = (f_out == hA) ? hB : hA;
        b_out = (b_out == hbfA) ? hbfB : hbfA;
    }

    logsoftmax_kernel<<<N_NODES / 4, 256, 0, stream>>>(hf_in, out);
}

// Round 9
// 754.762 us; speedup vs baseline: 1.2673x; 1.2673x over previous
//
#include <hip/hip_runtime.h>
#include <math.h>

#define N_NODES 50000
#define F_IN 256
#define HID 128
#define NH 8
#define HD 16
#define NCLS 64
#define NEDGE 1250000
#define NB 44
#define RATIO 0.15075567228888181f
#define EPS_F 1e-4f
#define NCHUNK 196   // ceil(N_NODES/256)
#define NROW (NCHUNK * 4)  // partial rows per head = 784

typedef short short8 __attribute__((ext_vector_type(8)));
typedef float f32x4 __attribute__((ext_vector_type(4)));
typedef unsigned short u16;

// ---------- helpers ----------
__device__ inline unsigned fkey(float f) {
    unsigned u = __float_as_uint(f);
    return (u & 0x80000000u) ? ~u : (u | 0x80000000u);
}
__device__ inline float funkey(unsigned k) {
    unsigned u = (k & 0x80000000u) ? (k ^ 0x80000000u) : ~k;
    return __uint_as_float(u);
}
__device__ inline float elu_f(float v) { return v > 0.f ? v : expm1f(v); }
__device__ inline u16 f2bf(float f) {
    unsigned u = __float_as_uint(f);
    unsigned r = (u + 0x7fffu + ((u >> 16) & 1u)) >> 16;  // RNE
    return (u16)r;
}

// ---------- convert data fp32 -> bf16 ----------
__global__ __launch_bounds__(256) void cvt_data_kernel(
    const float* __restrict__ d, u16* __restrict__ o)
{
    int idx = blockIdx.x * 256 + threadIdx.x;   // one per 8 floats
    if (idx >= N_NODES * 256 / 8) return;
    const float4* p = (const float4*)(d + (size_t)idx * 8);
    float4 v0 = p[0], v1 = p[1];
    u16 t[8];
    t[0] = f2bf(v0.x); t[1] = f2bf(v0.y); t[2] = f2bf(v0.z); t[3] = f2bf(v0.w);
    t[4] = f2bf(v1.x); t[5] = f2bf(v1.y); t[6] = f2bf(v1.z); t[7] = f2bf(v1.w);
    *(short8*)(o + (size_t)idx * 8) = *(short8*)t;
}

// ---------- pack W (transposed, bf16) + bias for fused QKV+lin1 GEMM ----------
__global__ __launch_bounds__(256) void pack_wt_kernel(
    const float* __restrict__ qw, const float* __restrict__ kw,
    const float* __restrict__ vw, const float* __restrict__ lw,
    const float* __restrict__ qb, const float* __restrict__ kb,
    const float* __restrict__ vb, const float* __restrict__ lb,
    u16* __restrict__ Wt, float* __restrict__ bcat)
{
    int idx = blockIdx.x * 256 + threadIdx.x;
    if (idx < 512 * 256) {
        int n = idx >> 8, k = idx & 255;
        int sel = n >> 7, jj = n & 127;
        const float* w = sel == 0 ? qw : sel == 1 ? kw : sel == 2 ? vw : lw;
        Wt[idx] = f2bf(w[k * 128 + jj]);
    }
    if (idx < 512) {
        int sel = idx >> 7, jj = idx & 127;
        const float* b = sel == 0 ? qb : sel == 1 ? kb : sel == 2 ? vb : lb;
        bcat[idx] = b[jj];
    }
}

// ---------- pack lin2_w transposed bf16 ----------
__global__ __launch_bounds__(256) void pack_wt2_kernel(
    const float* __restrict__ w2, const float* __restrict__ b2in,
    u16* __restrict__ Wt2, float* __restrict__ b2)
{
    int idx = blockIdx.x * 256 + threadIdx.x;
    if (idx < 64 * 256) {
        int n = idx >> 8, k = idx & 255;
        Wt2[idx] = f2bf(w2[k * 64 + n]);
    }
    if (idx < 64) b2[idx] = b2in[idx];
}

// ---------- bf16 MFMA GEMM1: sections 0=Q,1=K (fp32->B1qk), 2=V (bf16), 3=lin1 (elu bf16->hbuf) ----------
#define LDA 40
__global__ __launch_bounds__(256) void gemm1_mfma(
    const u16* __restrict__ A, const u16* __restrict__ Wt,
    const float* __restrict__ bias, float* __restrict__ B1qk,
    u16* __restrict__ Vbf, u16* __restrict__ hbuf, int M)
{
    __shared__ u16 As[128 * LDA];
    __shared__ u16 Bs[128 * LDA];
    int tid = threadIdx.x;
    int wave = tid >> 6, lane = tid & 63;
    int quad = lane >> 4, lrow = lane & 15;
    int m0 = blockIdx.x * 128;
    int sec = blockIdx.y;
    int n0 = sec * 128;
    int wm = (wave & 1) * 64, wn = (wave >> 1) * 64;

    f32x4 acc[4][4];
#pragma unroll
    for (int i = 0; i < 4; i++)
#pragma unroll
        for (int j = 0; j < 4; j++) acc[i][j] = (f32x4){0.f, 0.f, 0.f, 0.f};

    int r = tid >> 1;
    int cc = (tid & 1) * 16;

    for (int k0 = 0; k0 < 256; k0 += 32) {
        short8 x0 = (short8)0, x1 = (short8)0;
        int row = m0 + r;
        if (row < M) {
            const short8* p = (const short8*)(A + (size_t)row * 256 + k0 + cc);
            x0 = p[0]; x1 = p[1];
        }
        *(short8*)&As[r * LDA + cc] = x0;
        *(short8*)&As[r * LDA + cc + 8] = x1;
        const short8* q = (const short8*)(Wt + (size_t)(n0 + r) * 256 + k0 + cc);
        *(short8*)&Bs[r * LDA + cc] = q[0];
        *(short8*)&Bs[r * LDA + cc + 8] = q[1];
        __syncthreads();

        short8 af[4], bfr[4];
#pragma unroll
        for (int i = 0; i < 4; i++)
            af[i] = *(const short8*)&As[(wm + i * 16 + lrow) * LDA + quad * 8];
#pragma unroll
        for (int j = 0; j < 4; j++)
            bfr[j] = *(const short8*)&Bs[(wn + j * 16 + lrow) * LDA + quad * 8];
#pragma unroll
        for (int i = 0; i < 4; i++)
#pragma unroll
            for (int j = 0; j < 4; j++)
                acc[i][j] = __builtin_amdgcn_mfma_f32_16x16x32_bf16(af[i], bfr[j], acc[i][j], 0, 0, 0);
        __syncthreads();
    }

#pragma unroll
    for (int j = 0; j < 4; j++) {
        int col = wn + j * 16 + lrow;          // 0..127 within section
        float bj = bias[n0 + col];
#pragma unroll
        for (int i = 0; i < 4; i++) {
#pragma unroll
            for (int reg = 0; reg < 4; reg++) {
                int row = m0 + wm + i * 16 + quad * 4 + reg;
                if (row >= M) continue;
                float v = acc[i][j][reg] + bj;
                if (sec <= 1)      B1qk[(size_t)row * 256 + sec * 128 + col] = v;
                else if (sec == 2) Vbf[(size_t)row * 128 + col] = f2bf(v);
                else               hbuf[(size_t)row * 256 + col] = f2bf(elu_f(v));
            }
        }
    }
}

// ---------- bf16 MFMA GEMM2 (lin2): [N,256]@[256,64] + bias, elu -> xbuf fp32 + bf16 ----------
__global__ __launch_bounds__(256) void gemm2_mfma(
    const u16* __restrict__ A, const u16* __restrict__ Wt2,
    const float* __restrict__ b2, float* __restrict__ xbuf,
    u16* __restrict__ xbf, int M)
{
    __shared__ u16 As[128 * LDA];
    __shared__ u16 Bs[64 * LDA];
    int tid = threadIdx.x;
    int wave = tid >> 6, lane = tid & 63;
    int quad = lane >> 4, lrow = lane & 15;
    int m0 = blockIdx.x * 128;
    int wm = (wave & 1) * 64, wn = (wave >> 1) * 32;

    f32x4 acc[4][2];
#pragma unroll
    for (int i = 0; i < 4; i++)
#pragma unroll
        for (int j = 0; j < 2; j++) acc[i][j] = (f32x4){0.f, 0.f, 0.f, 0.f};

    int r = tid >> 1;
    int cc = (tid & 1) * 16;

    for (int k0 = 0; k0 < 256; k0 += 32) {
        short8 x0 = (short8)0, x1 = (short8)0;
        int row = m0 + r;
        if (row < M) {
            const short8* p = (const short8*)(A + (size_t)row * 256 + k0 + cc);
            x0 = p[0]; x1 = p[1];
        }
        *(short8*)&As[r * LDA + cc] = x0;
        *(short8*)&As[r * LDA + cc + 8] = x1;
        if (tid < 128) {
            const short8* q = (const short8*)(Wt2 + (size_t)r * 256 + k0 + cc);
            *(short8*)&Bs[r * LDA + cc] = q[0];
            *(short8*)&Bs[r * LDA + cc + 8] = q[1];
        }
        __syncthreads();

        short8 af[4], bfr[2];
#pragma unroll
        for (int i = 0; i < 4; i++)
            af[i] = *(const short8*)&As[(wm + i * 16 + lrow) * LDA + quad * 8];
#pragma unroll
        for (int j = 0; j < 2; j++)
            bfr[j] = *(const short8*)&Bs[(wn + j * 16 + lrow) * LDA + quad * 8];
#pragma unroll
        for (int i = 0; i < 4; i++)
#pragma unroll
            for (int j = 0; j < 2; j++)
                acc[i][j] = __builtin_amdgcn_mfma_f32_16x16x32_bf16(af[i], bfr[j], acc[i][j], 0, 0, 0);
        __syncthreads();
    }

#pragma unroll
    for (int j = 0; j < 2; j++) {
        int col = wn + j * 16 + lrow;   // 0..63
        float bj = b2[col];
#pragma unroll
        for (int i = 0; i < 4; i++) {
#pragma unroll
            for (int reg = 0; reg < 4; reg++) {
                int row = m0 + wm + i * 16 + quad * 4 + reg;
                if (row >= M) continue;
                float v = elu_f(acc[i][j][reg] + bj);
                xbuf[(size_t)row * 64 + col] = v;
                xbf[(size_t)row * 64 + col] = f2bf(v);
            }
        }
    }
}

// ---------- K-side global max of dash per head (proj via scalar loads) ----------
__global__ __launch_bounds__(256) void kmax_kernel(
    const float* __restrict__ B1qk, const float* __restrict__ proj,
    unsigned* __restrict__ kmax)
{
    __shared__ unsigned smax[NH];
    int tid = threadIdx.x;
    if (tid < NH) smax[tid] = 0u;
    __syncthreads();
    int g = blockIdx.x * 256 + tid;
    if (g < N_NODES * NH) {
        int n = g >> 3, h = g & 7;
        const float* kp = B1qk + (size_t)n * 256 + 128 + h * 16;
        float x[16];
#pragma unroll
        for (int i = 0; i < 16; i += 4) *(float4*)&x[i] = *(const float4*)(kp + i);
        float mx = -1e30f;
        for (int m = 0; m < NB; m++) {
            float d = 0.f;
#pragma unroll
            for (int i = 0; i < 16; i++) d += x[i] * proj[m * 16 + i];
            mx = fmaxf(mx, d);
        }
        atomicMax(&smax[h], fkey(mx * 0.5f));
    }
    __syncthreads();
    if (tid < NH) atomicMax(&kmax[tid], smax[tid]);
}

// ---------- K-side stage A: kp -> bf16 LDS -> MFMA -> per-wave partials (NO atomics) ----------
#define KLD 264   // LDS row stride (bf16 elems): 528B -> 4-bank shift/row, conflict-free b128
__global__ __launch_bounds__(256) void kstats_kernel(
    const float* __restrict__ B1qk, const u16* __restrict__ Vbf,
    const float* __restrict__ proj, const unsigned* __restrict__ kmax,
    float* __restrict__ partC, float* __restrict__ partK)
{
    __shared__ u16 kpT[48 * KLD];
    __shared__ u16 vT[16 * KLD];
    int h = blockIdx.y;
    int tid = threadIdx.x;
    int wave = tid >> 6, lane = tid & 63;
    int quad = lane >> 4, lrow = lane & 15;

    // zero the pad rows 44..47 of kpT (never written below)
    for (int i = tid; i < 4 * KLD / 2; i += 256) ((unsigned*)&kpT[44 * KLD])[i] = 0u;

    float M = funkey(kmax[h]);
    int n = blockIdx.x * 256 + tid;
    bool valid = n < N_NODES;
    float x[16];
    float diag = 0.f;
    if (valid) {
#pragma unroll
        for (int i = 0; i < 16; i += 4)
            *(float4*)&x[i] = *(const float4*)(B1qk + (size_t)n * 256 + 128 + h * 16 + i);
#pragma unroll
        for (int i = 0; i < 16; i++) diag += x[i] * x[i];
        diag *= 0.125f;
    }
#pragma unroll 4
    for (int m = 0; m < NB; m++) {
        float kp = 0.f;
        if (valid) {
            float d = 0.f;
#pragma unroll
            for (int i = 0; i < 16; i++) d += x[i] * proj[m * 16 + i];
            kp = RATIO * (expf(0.5f * d - diag - M) + EPS_F);
        }
        kpT[m * KLD + tid] = f2bf(kp);
    }
    // V row (already bf16)
    u16 vv[16];
    if (valid) {
        const short8* pv = (const short8*)(Vbf + (size_t)n * 128 + h * 16);
        *(short8*)&vv[0] = pv[0];
        *(short8*)&vv[8] = pv[1];
    } else {
#pragma unroll
        for (int i = 0; i < 16; i++) vv[i] = 0;
    }
#pragma unroll
    for (int d = 0; d < 16; d++) vT[d * KLD + tid] = vv[d];
    __syncthreads();

    f32x4 accC[3], accK[3];
#pragma unroll
    for (int t = 0; t < 3; t++) { accC[t] = (f32x4){0,0,0,0}; accK[t] = (f32x4){0,0,0,0}; }

    short8 ones = (short8)0;
    if (lrow == 0) {
#pragma unroll
        for (int i = 0; i < 8; i++) ones[i] = (short)0x3F80;  // bf16 1.0
    }

    // MFMA: this wave handles node-subchunks 2*wave, 2*wave+1 (K dim = nodes)
#pragma unroll
    for (int c2 = 0; c2 < 2; c2++) {
        int c = wave * 2 + c2;
        short8 bfr = *(const short8*)&vT[lrow * KLD + c * 32 + quad * 8];
#pragma unroll
        for (int t = 0; t < 3; t++) {
            short8 af = *(const short8*)&kpT[(t * 16 + lrow) * KLD + c * 32 + quad * 8];
            accC[t] = __builtin_amdgcn_mfma_f32_16x16x32_bf16(af, bfr, accC[t], 0, 0, 0);
            accK[t] = __builtin_amdgcn_mfma_f32_16x16x32_bf16(af, ones, accK[t], 0, 0, 0);
        }
    }

    // stream per-wave partials; entry e = m*16+col, row = h*784 + blockIdx.x*4 + wave
    int prow = (h * NCHUNK + blockIdx.x) * 4 + wave;
    float* P = partC + (size_t)prow * 768;
#pragma unroll
    for (int t = 0; t < 3; t++)
#pragma unroll
        for (int reg = 0; reg < 4; reg++)
            P[t * 256 + quad * 64 + reg * 16 + lrow] = accC[t][reg];
    if (lrow == 0) {
        float* P2 = partK + (size_t)prow * 48;
#pragma unroll
        for (int t = 0; t < 3; t++)
#pragma unroll
            for (int reg = 0; reg < 4; reg++)
                P2[t * 16 + quad * 4 + reg] = accK[t][reg];
    }
}

// ---------- K-side stage B: reduce partials -> ctx, kcum ----------
__global__ __launch_bounds__(256) void kreduce_kernel(
    const float* __restrict__ partC, const float* __restrict__ partK,
    float* __restrict__ kcum, float* __restrict__ ctx)
{
    int b = blockIdx.x;
    int tid = threadIdx.x;
    if (b < 24) {
        int g = b * 256 + tid;            // [0, 8*768)
        int h = g / 768, e = g % 768;
        int m = e >> 4, col = e & 15;
        const float* p = partC + (size_t)h * NROW * 768 + e;
        float s0 = 0.f, s1 = 0.f, s2 = 0.f, s3 = 0.f;
        for (int i = 0; i < NROW; i += 4) {
            s0 += p[(size_t)(i + 0) * 768];
            s1 += p[(size_t)(i + 1) * 768];
            s2 += p[(size_t)(i + 2) * 768];
            s3 += p[(size_t)(i + 3) * 768];
        }
        if (m < NB) ctx[h * NB * HD + m * 16 + col] = (s0 + s1) + (s2 + s3);
    } else {
        int g = (b - 24) * 256 + tid;     // need 8*48 = 384
        if (g < NH * 48) {
            int h = g / 48, m = g % 48;
            const float* p = partK + (size_t)h * NROW * 48 + m;
            float s0 = 0.f, s1 = 0.f, s2 = 0.f, s3 = 0.f;
            for (int i = 0; i < NROW; i += 4) {
                s0 += p[(size_t)(i + 0) * 48];
                s1 += p[(size_t)(i + 1) * 48];
                s2 += p[(size_t)(i + 2) * 48];
                s3 += p[(size_t)(i + 3) * 48];
            }
            if (m < NB) kcum[h * NB + m] = (s0 + s1) + (s2 + s3);
        }
    }
}

// ---------- Q-side + attention output (scalar proj/ctx/kcum, bf16 out to hbuf) ----------
__global__ __launch_bounds__(256) void attn_out_kernel(
    const float* __restrict__ B1qk, const float* __restrict__ proj,
    const float* __restrict__ kcum, const float* __restrict__ ctx,
    u16* __restrict__ hbuf)
{
    int h = blockIdx.y;
    int tid = threadIdx.x;
    int n = blockIdx.x * 256 + tid;
    if (n >= N_NODES) return;
    float x[16];
#pragma unroll
    for (int i = 0; i < 16; i += 4)
        *(float4*)&x[i] = *(const float4*)(B1qk + (size_t)n * 256 + h * 16 + i);
    float diag = 0.f;
#pragma unroll
    for (int i = 0; i < 16; i++) diag += x[i] * x[i];
    diag *= 0.125f;
    float dash[NB];
    float mx = -1e30f;
#pragma unroll 4
    for (int m = 0; m < NB; m++) {
        float d = 0.f;
#pragma unroll
        for (int i = 0; i < 16; i++) d += x[i] * proj[m * 16 + i];
        d *= 0.5f;
        dash[m] = d;
        mx = fmaxf(mx, d);
    }
    float den = 0.f;
    float outv[16];
#pragma unroll
    for (int d = 0; d < 16; d++) outv[d] = 0.f;
#pragma unroll 4
    for (int m = 0; m < NB; m++) {
        float q = RATIO * (expf(dash[m] - diag - mx) + EPS_F);
        den += q * kcum[h * NB + m];
#pragma unroll
        for (int d = 0; d < 16; d++) outv[d] += q * ctx[h * NB * HD + m * 16 + d];
    }
    float dinv = 1.f / den;
    u16 ob[16];
#pragma unroll
    for (int d = 0; d < 16; d++) ob[d] = f2bf(elu_f(outv[d] * dinv));
    u16* dst = hbuf + (size_t)n * 256 + 128 + h * 16;
    *(short8*)dst = *(short8*)&ob[0];
    *(short8*)(dst + 8) = *(short8*)&ob[8];
}

// ---------- APPNP: degree / dis / scan / CSR fill / hop ----------
__global__ __launch_bounds__(256) void deg_kernel(const int* __restrict__ ei, unsigned* __restrict__ deg)
{
    int e = blockIdx.x * 256 + threadIdx.x;
    if (e < NEDGE) atomicAdd(&deg[ei[NEDGE + e]], 1u);
}
__global__ __launch_bounds__(256) void dis_kernel(const unsigned* __restrict__ deg, float* __restrict__ dis)
{
    int i = blockIdx.x * 256 + threadIdx.x;
    if (i < N_NODES) dis[i] = rsqrtf((float)(deg[i] + 1u));
}
__global__ __launch_bounds__(256) void scan1_kernel(const unsigned* __restrict__ deg, unsigned* __restrict__ bsum)
{
    __shared__ unsigned s[256];
    int i = blockIdx.x * 256 + threadIdx.x;
    unsigned v = (i < N_NODES) ? deg[i] : 0u;
    s[threadIdx.x] = v;
    __syncthreads();
    for (int d = 128; d > 0; d >>= 1) {
        if (threadIdx.x < d) s[threadIdx.x] += s[threadIdx.x + d];
        __syncthreads();
    }
    if (threadIdx.x == 0) bsum[blockIdx.x] = s[0];
}
__global__ __launch_bounds__(256) void scan2_kernel(const unsigned* __restrict__ bsum, unsigned* __restrict__ boff, int nb)
{
    __shared__ unsigned s[256];
    int t = threadIdx.x;
    unsigned v = (t < nb) ? bsum[t] : 0u;
    s[t] = v;
    __syncthreads();
    for (int d = 1; d < 256; d <<= 1) {
        unsigned x = (t >= d) ? s[t - d] : 0u;
        __syncthreads();
        s[t] += x;
        __syncthreads();
    }
    boff[t] = s[t] - v;
}
__global__ __launch_bounds__(256) void scan3_kernel(
    const unsigned* __restrict__ deg, const unsigned* __restrict__ boff,
    unsigned* __restrict__ offsets)
{
    __shared__ unsigned s[256];
    int t = threadIdx.x;
    int i = blockIdx.x * 256 + t;
    unsigned v = (i < N_NODES) ? deg[i] : 0u;
    s[t] = v;
    __syncthreads();
    for (int d = 1; d < 256; d <<= 1) {
        unsigned x = (t >= d) ? s[t - d] : 0u;
        __syncthreads();
        s[t] += x;
        __syncthreads();
    }
    unsigned excl = s[t] - v + boff[blockIdx.x];
    if (i < N_NODES) offsets[i] = excl;
    if (i == N_NODES - 1) offsets[N_NODES] = excl + v;
}
__global__ __launch_bounds__(256) void fill_csr_kernel(
    const int* __restrict__ ei, const unsigned* __restrict__ offsets,
    unsigned* __restrict__ cursor, const float* __restrict__ dis,
    int2* __restrict__ csr_ed)
{
    int e = blockIdx.x * 256 + threadIdx.x;
    if (e >= NEDGE) return;
    int r = ei[e], c = ei[NEDGE + e];
    unsigned pos = offsets[c] + atomicAdd(&cursor[c], 1u);
    csr_ed[pos] = make_int2(r, __float_as_int(dis[r] * dis[c]));
}
// one wave per node; bf16 gathers, 2 edges per instruction (halves), and
// explicit 8-deep load batching so 8 gathers are in flight per wave
__global__ __launch_bounds__(256) void hop_kernel(
    const u16* __restrict__ hbf, const float* __restrict__ hf,
    const float* __restrict__ x0,
    const unsigned* __restrict__ offsets, const int2* __restrict__ edges,
    const float* __restrict__ dis,
    float* __restrict__ hf_out, u16* __restrict__ hbf_out)
{
    int wave = threadIdx.x >> 6, lane = threadIdx.x & 63;
    int n = blockIdx.x * 4 + wave;
    if (n >= N_NODES) return;
    int half = lane >> 5, fl = lane & 31;   // half: even/odd edges; fl: feature pair
    unsigned e0 = offsets[n], e1 = offsets[n + 1];
    float ax = 0.f, ay = 0.f;
    unsigned e = e0;
    while (e < e1) {
        unsigned cnt = min(64u, e1 - e);
        int2 ev = ((unsigned)lane < cnt) ? edges[e + lane] : make_int2(0, 0);
        unsigned npair = (cnt + 1) >> 1;
        for (unsigned p = 0; p < npair; p += 8) {
            unsigned bu[8];
            float bw[8];
            // address/load phase: 8 independent gathers issued back-to-back.
            // pads (2*(p+t)+half >= cnt) clamp to lane 63 which is zero-filled
            // whenever cnt < 64 (when cnt == 64 there are no pads): s=0, w=0.
#pragma unroll
            for (int t = 0; t < 8; t++) {
                int jj = 2 * (int)(p + t) + half;
                jj = jj > 63 ? 63 : jj;
                int s = __shfl(ev.x, jj);
                bw[t] = __int_as_float(__shfl(ev.y, jj));
                bu[t] = *(const unsigned*)(hbf + (size_t)s * 64 + fl * 2);
            }
            // accumulate phase
#pragma unroll
            for (int t = 0; t < 8; t++) {
                float lo = __uint_as_float(bu[t] << 16);
                float hi = __uint_as_float(bu[t] & 0xffff0000u);
                ax += bw[t] * lo;
                ay += bw[t] * hi;
            }
        }
        e += cnt;
    }
    // combine even/odd halves
    ax += __shfl_xor(ax, 32);
    ay += __shfl_xor(ay, 32);
    if (half == 0) {
        float dn = dis[n];
        float2 hs = *(const float2*)(hf + (size_t)n * 64 + fl * 2);
        float2 xs = *(const float2*)(x0 + (size_t)n * 64 + fl * 2);
        float rx = 0.9f * (ax + dn * dn * hs.x) + 0.1f * xs.x;
        float ry = 0.9f * (ay + dn * dn * hs.y) + 0.1f * xs.y;
        *(float2*)(hf_out + (size_t)n * 64 + fl * 2) = make_float2(rx, ry);
        unsigned pu = (unsigned)f2bf(rx) | ((unsigned)f2bf(ry) << 16);
        *(unsigned*)(hbf_out + (size_t)n * 64 + fl * 2) = pu;
    }
}

// ---------- log_softmax + raw copy ----------
__global__ __launch_bounds__(256) void logsoftmax_kernel(
    const float* __restrict__ hf, float* __restrict__ out)
{
    int wave = threadIdx.x >> 6, lane = threadIdx.x & 63;
    int n = blockIdx.x * 4 + wave;
    if (n >= N_NODES) return;
    float v = hf[(size_t)n * 64 + lane];
    float m = v;
    for (int d = 32; d > 0; d >>= 1) m = fmaxf(m, __shfl_xor(m, d));
    float ex = expf(v - m);
    float ssum = ex;
    for (int d = 32; d > 0; d >>= 1) ssum += __shfl_xor(ssum, d);
    out[(size_t)n * 64 + lane] = v - m - logf(ssum);
    out[(size_t)N_NODES * 64 + (size_t)n * 64 + lane] = v;
}

// ---------- launcher ----------
static inline size_t align256(size_t x) { return (x + 255) & ~(size_t)255; }

extern "C" void kernel_launch(void* const* d_in, const int* in_sizes, int n_in,
                              void* d_out, int out_size, void* d_ws, size_t ws_size,
                              hipStream_t stream)
{
    const float* data   = (const float*)d_in[0];
    const int*   ei     = (const int*)d_in[1];
    const float* lin1_w = (const float*)d_in[2];
    const float* lin1_b = (const float*)d_in[3];
    const float* lin2_w = (const float*)d_in[4];
    const float* lin2_b = (const float*)d_in[5];
    const float* q_w = (const float*)d_in[6];
    const float* q_b = (const float*)d_in[7];
    const float* k_w = (const float*)d_in[8];
    const float* k_b = (const float*)d_in[9];
    const float* v_w = (const float*)d_in[10];
    const float* v_b = (const float*)d_in[11];
    const float* proj = (const float*)d_in[12];
    float* out = (float*)d_out;

    char* w = (char*)d_ws;
    auto alloc = [&](size_t bytes) { char* p = w; w += align256(bytes); return p; };
    float*    B1qk    = (float*)alloc((size_t)N_NODES * 256 * 4);
    u16*      Abf     = (u16*)alloc((size_t)N_NODES * 256 * 2);
    u16*      Wt      = (u16*)alloc(512 * 256 * 2);
    float*    bcat    = (float*)alloc(512 * 4);
    u16*      Wt2     = (u16*)alloc(64 * 256 * 2);
    float*    b2      = (float*)alloc(64 * 4);
    u16*      Vbf     = (u16*)alloc((size_t)N_NODES * 128 * 2);
    u16*      hbuf    = (u16*)alloc((size_t)N_NODES * 256 * 2);
    unsigned* kmax    = (unsigned*)alloc(NH * 4);
    float*    kcum    = (float*)alloc((NH * NB + NH * NB * HD) * 4);
    float*    ctx     = kcum + NH * NB;
    float*    partC   = (float*)alloc((size_t)NH * NROW * 768 * 4);
    float*    partK   = (float*)alloc((size_t)NH * NROW * 48 * 4);
    float*    xbuf    = (float*)alloc((size_t)N_NODES * 64 * 4);
    u16*      xbf     = (u16*)alloc((size_t)N_NODES * 64 * 2);
    float*    hA      = (float*)alloc((size_t)N_NODES * 64 * 4);
    float*    hB      = (float*)alloc((size_t)N_NODES * 64 * 4);
    u16*      hbfA    = (u16*)alloc((size_t)N_NODES * 64 * 2);
    u16*      hbfB    = (u16*)alloc((size_t)N_NODES * 64 * 2);
    unsigned* deg     = (unsigned*)alloc((size_t)N_NODES * 4);
    float*    dis     = (float*)alloc((size_t)N_NODES * 4);
    unsigned* offsets = (unsigned*)alloc((size_t)(N_NODES + 1) * 4);
    unsigned* cursor  = (unsigned*)alloc((size_t)N_NODES * 4);
    unsigned* bsum    = (unsigned*)alloc(256 * 4);
    unsigned* boff    = (unsigned*)alloc(256 * 4);
    int2*     csr_ed  = (int2*)alloc((size_t)NEDGE * 8);

    hipMemsetAsync(kmax, 0, NH * 4, stream);
    hipMemsetAsync(deg, 0, (size_t)N_NODES * 4, stream);
    hipMemsetAsync(cursor, 0, (size_t)N_NODES * 4, stream);

    cvt_data_kernel<<<(N_NODES * 256 / 8 + 255) / 256, 256, 0, stream>>>(data, Abf);
    pack_wt_kernel<<<512, 256, 0, stream>>>(q_w, k_w, v_w, lin1_w, q_b, k_b, v_b, lin1_b, Wt, bcat);
    pack_wt2_kernel<<<64, 256, 0, stream>>>(lin2_w, lin2_b, Wt2, b2);

    gemm1_mfma<<<dim3((N_NODES + 127) / 128, 4), 256, 0, stream>>>(
        Abf, Wt, bcat, B1qk, Vbf, hbuf, N_NODES);

    kmax_kernel<<<(N_NODES * NH + 255) / 256, 256, 0, stream>>>(B1qk, proj, kmax);
    kstats_kernel<<<dim3(NCHUNK, NH), 256, 0, stream>>>(
        B1qk, Vbf, proj, kmax, partC, partK);
    kreduce_kernel<<<26, 256, 0, stream>>>(partC, partK, kcum, ctx);
    attn_out_kernel<<<dim3((N_NODES + 255) / 256, NH), 256, 0, stream>>>(
        B1qk, proj, kcum, ctx, hbuf);

    gemm2_mfma<<<dim3((N_NODES + 127) / 128, 1), 256, 0, stream>>>(
        hbuf, Wt2, b2, xbuf, xbf, N_NODES);

    // APPNP prep
    deg_kernel<<<(NEDGE + 255) / 256, 256, 0, stream>>>(ei, deg);
    dis_kernel<<<(N_NODES + 255) / 256, 256, 0, stream>>>(deg, dis);
    int nscan = (N_NODES + 255) / 256;
    scan1_kernel<<<nscan, 256, 0, stream>>>(deg, bsum);
    scan2_kernel<<<1, 256, 0, stream>>>(bsum, boff, nscan);
    scan3_kernel<<<nscan, 256, 0, stream>>>(deg, boff, offsets);
    fill_csr_kernel<<<(NEDGE + 255) / 256, 256, 0, stream>>>(ei, offsets, cursor, dis, csr_ed);

    // 10 hops, ping-pong (bf16 gather table + fp32 carry)
    const float* hf_in = xbuf;
    const u16*   hb_in = xbf;
    float* f_out = hA;
    u16*   b_out = hbfA;
    for (int hop = 0; hop < 10; hop++) {
        hop_kernel<<<N_NODES / 4, 256, 0, stream>>>(
            hb_in, hf_in, xbuf, offsets, csr_ed, dis, f_out, b_out);
        hf_in = f_out;
        hb_in = b_out;
        f_out = (f_out == hA) ? hB : hA;
        b_out = (b_out == hbfA) ? hbfB : hbfA;
    }

    logsoftmax_kernel<<<N_NODES / 4, 256, 0, stream>>>(hf_in, out);
}